// Round 3
// baseline (687.087 us; speedup 1.0000x reference)
//
#include <hip/hip_runtime.h>
#include <stdint.h>

#define D_DIM 1024     // D_IN == D_MODEL == 1024
#define BT    32768    // 8*4096
#define NCHUNK 32      // 4096/128 chunks per batch

typedef __attribute__((ext_vector_type(8))) short short8;
typedef __attribute__((ext_vector_type(4))) float f32x4;

__device__ __forceinline__ ushort f2bf(float f) {
  union { float f; uint32_t u; } v; v.f = f;
  uint32_t u = v.u + 0x7fffu + ((v.u >> 16) & 1u);
  return (ushort)(u >> 16);
}

// ---------------- x (B,T,1024) fp32 -> bf16 ----------------
__global__ void cvt_x_kernel(const float4* __restrict__ x, ushort4* __restrict__ o, int n4) {
  int i = blockIdx.x * blockDim.x + threadIdx.x;
  if (i < n4) {
    float4 f = x[i];
    ushort4 r;
    r.x = f2bf(f.x); r.y = f2bf(f.y); r.z = f2bf(f.z); r.w = f2bf(f.w);
    o[i] = r;
  }
}

// ---------------- W (K,N) fp32 -> WT (3,N,K) bf16 ----------------
__global__ void transpose_w_kernel(const float* __restrict__ W0, const float* __restrict__ W1,
                                   const float* __restrict__ W2, ushort* __restrict__ WT) {
  __shared__ float tile[32][33];
  const float* W = (blockIdx.z == 0) ? W0 : ((blockIdx.z == 1) ? W1 : W2);
  int x0 = blockIdx.x * 32, y0 = blockIdx.y * 32;   // x0: n-block, y0: k-block
  for (int i = threadIdx.y; i < 32; i += 8)
    tile[i][threadIdx.x] = W[(size_t)(y0 + i) * D_DIM + x0 + threadIdx.x];
  __syncthreads();
  ushort* O = WT + (size_t)blockIdx.z * D_DIM * D_DIM;
  for (int i = threadIdx.y; i < 32; i += 8)
    O[(size_t)(x0 + i) * D_DIM + y0 + threadIdx.x] = f2bf(tile[threadIdx.x][i]);
}

// ---------------- fused GEMM(x3) + pointwise + chunk scan ----------------
__device__ __forceinline__ void async16(const void* g, void* l) {
  __builtin_amdgcn_global_load_lds((const __attribute__((address_space(1))) void*)g,
                                   (__attribute__((address_space(3))) void*)l, 16, 0, 0);
}

__device__ __forceinline__ float softplusf(float x) {
  return fmaxf(x, 0.f) + log1pf(expf(-fabsf(x)));
}

// Block: 256 threads (4 waves, 2x2 wave grid). Tile: 128(t) x 64(d), BK=32.
// Three accumulator sets (lam/del/u) share the x staging.
__global__ __launch_bounds__(256, 2) void gemm_scan_kernel(
    const ushort* __restrict__ xb, const ushort* __restrict__ wt,
    const float* __restrict__ b_lam, const float* __restrict__ b_del,
    const float* __restrict__ b_B, float* __restrict__ Ac, float* __restrict__ Sc) {
  __shared__ __align__(16) char smem[32768];
  const int tid  = threadIdx.x;
  const int lane = tid & 63, wid = tid >> 6;
  const int wr = wid >> 1, wc = wid & 1;
  const int lhi = lane >> 4, llo = lane & 15;
  const int M0 = blockIdx.x * 128, N0 = blockIdx.y * 64;

  f32x4 acc[3][4][2];
#pragma unroll
  for (int g = 0; g < 3; ++g)
#pragma unroll
    for (int fr = 0; fr < 4; ++fr)
#pragma unroll
      for (int fc = 0; fc < 2; ++fc)
        acc[g][fr][fc] = (f32x4){0.f, 0.f, 0.f, 0.f};

  for (int k0 = 0; k0 < D_DIM; k0 += 32) {
    __syncthreads();   // previous iter's frag reads done before overwrite
    {
      // x tile [128][32] bf16 = 512 x 16B chunks, 2 rounds of 256
      int c0 = wid * 64 + lane;
      const ushort* g0 = xb + (size_t)(M0 + (c0 >> 2)) * D_DIM + k0 + (c0 & 3) * 8;
      async16(g0, smem + (wid * 64) * 16);
      int c1 = 256 + wid * 64 + lane;
      const ushort* g1 = xb + (size_t)(M0 + (c1 >> 2)) * D_DIM + k0 + (c1 & 3) * 8;
      async16(g1, smem + 4096 + (wid * 64) * 16);
      // W tiles [3][64][32] bf16, one round per group
      int cw = wid * 64 + lane;
#pragma unroll
      for (int g = 0; g < 3; ++g) {
        const ushort* gw = wt + (size_t)(g * D_DIM + N0 + (cw >> 2)) * D_DIM + k0 + (cw & 3) * 8;
        async16(gw, smem + 8192 + g * 4096 + (wid * 64) * 16);
      }
    }
    __syncthreads();   // compiler drains vmcnt before s_barrier -> staged data visible

    const char* xs  = smem;
    const char* wsm = smem + 8192;
    short8 af[4];
#pragma unroll
    for (int fr = 0; fr < 4; ++fr)
      af[fr] = *(const short8*)(xs + ((wr * 64 + fr * 16 + llo) * 32 + lhi * 8) * 2);
    short8 bfr[3][2];
#pragma unroll
    for (int g = 0; g < 3; ++g)
#pragma unroll
      for (int fc = 0; fc < 2; ++fc)
        bfr[g][fc] = *(const short8*)(wsm + (g * 2048 + (wc * 32 + fc * 16 + llo) * 32 + lhi * 8) * 2);
#pragma unroll
    for (int g = 0; g < 3; ++g)
#pragma unroll
      for (int fr = 0; fr < 4; ++fr)
#pragma unroll
        for (int fc = 0; fc < 2; ++fc)
          acc[g][fr][fc] = __builtin_amdgcn_mfma_f32_16x16x32_bf16(
              af[fr], bfr[g][fc], acc[g][fr][fc], 0, 0, 0);
  }
  __syncthreads();   // all frag reads done before epilogue overwrites LDS

  // Epilogue: alpha/drive into LDS in two 64-row halves, 64 threads scan columns.
  float* la  = (float*)smem;            // [64][64] alpha
  float* ldv = (float*)(smem + 16384);  // [64][64] drive
  float A = 1.f, S = 0.f;
#pragma unroll
  for (int half = 0; half < 2; ++half) {
    if (wr == half) {
#pragma unroll
      for (int fc = 0; fc < 2; ++fc) {
        int col = wc * 32 + fc * 16 + llo;
        int d = N0 + col;
        float bl = b_lam[d], bd = b_del[d], bu = b_B[d];
#pragma unroll
        for (int fr = 0; fr < 4; ++fr) {
#pragma unroll
          for (int j = 0; j < 4; ++j) {
            int row = fr * 16 + lhi * 4 + j;   // local row within half
            float lam = softplusf(acc[0][fr][fc][j] + bl);
            float de  = softplusf(acc[1][fr][fc][j] + bd);
            float uu  = acc[2][fr][fc][j] + bu;
            la[row * 64 + col]  = expf(-de * lam);
            ldv[row * 64 + col] = de * uu;
          }
        }
      }
    }
    __syncthreads();
    if (tid < 64) {
      for (int r = 0; r < 64; ++r) {
        float a  = la[r * 64 + tid];
        float dd = ldv[r * 64 + tid];
        S = fmaf(a, S, dd);
        A *= a;
      }
    }
    __syncthreads();
  }
  if (tid < 64) {
    int b  = M0 >> 12;          // 4096 rows per batch
    int cb = (M0 >> 7) & 31;    // chunk within batch
    size_t o = (size_t)(b * NCHUNK + cb) * D_DIM + N0 + tid;
    Ac[o] = A;
    Sc[o] = S;
  }
}

// ---------------- cross-chunk combine + output projections ----------------
__global__ __launch_bounds__(1024) void combine_project_kernel(
    const float* __restrict__ Ac, const float* __restrict__ Sc,
    const float* __restrict__ Wpar, const float* __restrict__ bpar,
    const float* __restrict__ Wadd, const float* __restrict__ badd,
    float* __restrict__ out) {
  int b = blockIdx.x, d = threadIdx.x;
  size_t base = (size_t)b * NCHUNK * D_DIM + d;
  float s = 0.f;
#pragma unroll 4
  for (int c = 0; c < NCHUNK; ++c)
    s = fmaf(Ac[base + (size_t)c * D_DIM], s, Sc[base + (size_t)c * D_DIM]);
  float p0 = s * Wpar[2 * d], p1 = s * Wpar[2 * d + 1], pa = s * Wadd[d];
#pragma unroll
  for (int off = 32; off; off >>= 1) {
    p0 += __shfl_xor(p0, off, 64);
    p1 += __shfl_xor(p1, off, 64);
    pa += __shfl_xor(pa, off, 64);
  }
  __shared__ float r0[16], r1[16], r2[16];
  int wid = threadIdx.x >> 6, lane = threadIdx.x & 63;
  if (lane == 0) { r0[wid] = p0; r1[wid] = p1; r2[wid] = pa; }
  __syncthreads();
  if (threadIdx.x == 0) {
    float a = bpar[0], bb = bpar[1], cc = badd[0];
    for (int i = 0; i < 16; ++i) { a += r0[i]; bb += r1[i]; cc += r2[i]; }
    out[b * 2 + 0] = a;       // parity_logits (8,2) flat first
    out[b * 2 + 1] = bb;
    out[16 + b]    = cc;      // add_pred (8,1) after
  }
}

extern "C" void kernel_launch(void* const* d_in, const int* in_sizes, int n_in,
                              void* d_out, int out_size, void* d_ws, size_t ws_size,
                              hipStream_t stream) {
  const float* x     = (const float*)d_in[0];
  const float* W_lam = (const float*)d_in[1];
  const float* b_lam = (const float*)d_in[2];
  const float* W_del = (const float*)d_in[3];
  const float* b_del = (const float*)d_in[4];
  const float* W_B   = (const float*)d_in[5];
  const float* b_B   = (const float*)d_in[6];
  const float* W_par = (const float*)d_in[7];
  const float* b_par = (const float*)d_in[8];
  const float* W_add = (const float*)d_in[9];
  const float* b_add = (const float*)d_in[10];

  char* ws = (char*)d_ws;
  ushort* xb = (ushort*)ws;                          // 64 MB bf16 x
  ushort* wt = (ushort*)(ws + 67108864);             // 6 MB  bf16 WT[3][n][k]
  float*  Ac = (float*)(ws + 73400320);              // 1 MB  chunk A
  float*  Sc = (float*)(ws + 74448896);              // 1 MB  chunk S

  int n4 = (BT * D_DIM) / 4;   // 8388608
  cvt_x_kernel<<<n4 / 256, 256, 0, stream>>>((const float4*)x, (ushort4*)xb, n4);
  transpose_w_kernel<<<dim3(32, 32, 3), dim3(32, 8, 1), 0, stream>>>(W_lam, W_del, W_B, wt);
  gemm_scan_kernel<<<dim3(BT / 128, D_DIM / 64), 256, 0, stream>>>(
      xb, wt, b_lam, b_del, b_B, Ac, Sc);
  combine_project_kernel<<<8, 1024, 0, stream>>>(Ac, Sc, W_par, b_par, W_add, b_add,
                                                 (float*)d_out);
}